// Round 1
// baseline (824.816 us; speedup 1.0000x reference)
//
#include <hip/hip_runtime.h>
#include <cstdint>
#include <cstring>

typedef short short8 __attribute__((ext_vector_type(8)));
typedef float float4v __attribute__((ext_vector_type(4)));
typedef float float4g __attribute__((ext_vector_type(4)));
typedef unsigned short ushort4v __attribute__((ext_vector_type(4)));

static __device__ __forceinline__ float b2f(unsigned short u) {
    unsigned int x = ((unsigned int)u) << 16;
    float f;
    __builtin_memcpy(&f, &x, 4);
    return f;
}
static __device__ __forceinline__ unsigned short f2b(float f) {
    unsigned int x;
    __builtin_memcpy(&x, &f, 4);
    unsigned int r = (x + 0x7fffu + ((x >> 16) & 1u)) >> 16;
    return (unsigned short)r;
}

// ---------------- fp32 -> bf16 convert ----------------
__global__ __launch_bounds__(256) void k_f2b(const float* __restrict__ in,
                                             unsigned short* __restrict__ out, int n) {
    int i = (blockIdx.x * 256 + threadIdx.x) * 4;
    if (i >= n) return;
    float4g v = *(const float4g*)(in + i);
    ushort4v r;
    r.x = f2b(v.x); r.y = f2b(v.y); r.z = f2b(v.z); r.w = f2b(v.w);
    *(ushort4v*)(out + i) = r;
}

// ---------------- generic bf16 GEMM: C[M,N] = A[M,K] @ W[N,K]^T ----------------
// grid: (ceil(N/128), M/128), block 256 (4 waves, each 64x64)
__global__ __launch_bounds__(256, 2)
void k_gemm_bt(const unsigned short* __restrict__ A, int lda,
               const unsigned short* __restrict__ W,
               void* __restrict__ C, int ldc,
               int N, int K, int c_fp32) {
    __shared__ __align__(16) unsigned short As[128 * 40];
    __shared__ __align__(16) unsigned short Ws[128 * 40];
    const int tid = threadIdx.x;
    const int m0 = blockIdx.y * 128, n0 = blockIdx.x * 128;
    const int wave = tid >> 6, lane = tid & 63;
    const int wm = (wave >> 1) * 64, wn = (wave & 1) * 64;
    const int lrow = lane & 15, lko = (lane >> 4) * 8;
    const int srow = tid >> 2, scol = (tid & 3) * 8;

    float4v acc[4][4];
    float4v z = {0.f, 0.f, 0.f, 0.f};
#pragma unroll
    for (int i = 0; i < 4; i++)
#pragma unroll
        for (int j = 0; j < 4; j++) acc[i][j] = z;

    for (int k0 = 0; k0 < K; k0 += 32) {
#pragma unroll
        for (int r = 0; r < 2; ++r) {
            int row = srow + r * 64;
            *(short8*)&As[row * 40 + scol] =
                *(const short8*)&A[(size_t)(m0 + row) * lda + k0 + scol];
            int wr = n0 + row;
            if (wr > N - 1) wr = N - 1;
            *(short8*)&Ws[row * 40 + scol] =
                *(const short8*)&W[(size_t)wr * K + k0 + scol];
        }
        __syncthreads();
        short8 af[4], bfr[4];
#pragma unroll
        for (int i = 0; i < 4; i++)
            af[i] = *(const short8*)&As[(wm + i * 16 + lrow) * 40 + lko];
#pragma unroll
        for (int i = 0; i < 4; i++)
            bfr[i] = *(const short8*)&Ws[(wn + i * 16 + lrow) * 40 + lko];
#pragma unroll
        for (int i = 0; i < 4; i++)
#pragma unroll
            for (int j = 0; j < 4; j++)
                acc[i][j] = __builtin_amdgcn_mfma_f32_16x16x32_bf16(af[i], bfr[j], acc[i][j], 0, 0, 0);
        __syncthreads();
    }

    const int rbase = (lane >> 4) * 4;
#pragma unroll
    for (int i = 0; i < 4; i++) {
#pragma unroll
        for (int j = 0; j < 4; j++) {
            int col = n0 + wn + j * 16 + lrow;
            if (col >= N) continue;
#pragma unroll
            for (int r = 0; r < 4; r++) {
                int row = m0 + wm + i * 16 + rbase + r;
                float v = acc[i][j][r];
                if (c_fp32)
                    ((float*)C)[(size_t)row * ldc + col] = v;
                else
                    ((unsigned short*)C)[(size_t)row * ldc + col] = f2b(v);
            }
        }
    }
}

// ---------------- RMSNorm in-place over first n cols of a row (stride ld) ----------------
__global__ __launch_bounds__(256) void k_rmsnorm(unsigned short* __restrict__ x,
                                                 const float* __restrict__ g, int ld, int n) {
    int row = blockIdx.x;
    int tid = threadIdx.x;
    size_t base = (size_t)row * ld;
    float ss = 0.f;
    for (int c = tid; c < n; c += 256) {
        float v = b2f(x[base + c]);
        ss += v * v;
    }
    for (int off = 32; off > 0; off >>= 1) ss += __shfl_xor(ss, off);
    __shared__ float wsum[4];
    int wave = tid >> 6, lane = tid & 63;
    if (lane == 0) wsum[wave] = ss;
    __syncthreads();
    ss = wsum[0] + wsum[1] + wsum[2] + wsum[3];
    float scale = rsqrtf(ss / (float)n + 1e-6f);
    for (int c = tid; c < n; c += 256) {
        float v = b2f(x[base + c]);
        x[base + c] = f2b(v * scale * g[c]);
    }
}

// ---------------- RoPE on q_pe: q[token, h*192+128 .. +192) in place ----------------
__global__ __launch_bounds__(256) void k_rope_q(unsigned short* __restrict__ q) {
    int idx = blockIdx.x * 256 + threadIdx.x;  // 4096*16*32
    int d = idx & 31;
    int h = (idx >> 5) & 15;
    int t = idx >> 9;
    int s = t & 2047;
    size_t base = (size_t)t * 3072 + h * 192 + 128;
    float inv = powf(10000.0f, -(float)(2 * d) * (1.0f / 64.0f));
    float f = (float)s * inv;
    float c = cosf(f), sn = sinf(f);
    float x1 = b2f(q[base + d]), x2 = b2f(q[base + d + 32]);
    q[base + d] = f2b(x1 * c - x2 * sn);
    q[base + d + 32] = f2b(x2 * c + x1 * sn);
}

// ---------------- RoPE on k_pe: ckv[token, 512..576) in place ----------------
__global__ __launch_bounds__(256) void k_rope_k(unsigned short* __restrict__ ckv) {
    int idx = blockIdx.x * 256 + threadIdx.x;  // 4096*32
    int d = idx & 31;
    int t = idx >> 5;
    int s = t & 2047;
    size_t base = (size_t)t * 576 + 512;
    float inv = powf(10000.0f, -(float)(2 * d) * (1.0f / 64.0f));
    float f = (float)s * inv;
    float c = cosf(f), sn = sinf(f);
    float x1 = b2f(ckv[base + d]), x2 = b2f(ckv[base + d + 32]);
    ckv[base + d] = f2b(x1 * c - x2 * sn);
    ckv[base + d + 32] = f2b(x2 * c + x1 * sn);
}

// ---------------- V transpose: vt[bh][d][s] = kv[(b*2048+s)*4096 + h*256+128+d] ----------------
// grid (64 s-tiles, 4 d-tiles, 32 bh), block 256 (32x8)
__global__ __launch_bounds__(256) void k_transpose_v(const unsigned short* __restrict__ kv,
                                                     unsigned short* __restrict__ vt) {
    int bh = blockIdx.z;
    int b = bh >> 4, h = bh & 15;
    int s0 = blockIdx.x * 32, d0 = blockIdx.y * 32;
    __shared__ unsigned short t[32][33];
    int tx = threadIdx.x & 31, ty = threadIdx.x >> 5;
#pragma unroll
    for (int i = 0; i < 4; i++) {
        int s = s0 + ty + i * 8;
        t[ty + i * 8][tx] = kv[(size_t)(b * 2048 + s) * 4096 + h * 256 + 128 + d0 + tx];
    }
    __syncthreads();
#pragma unroll
    for (int i = 0; i < 4; i++) {
        int d = d0 + ty + i * 8;
        vt[((size_t)bh * 128 + d) * 2048 + s0 + tx] = t[tx][ty + i * 8];
    }
}

// ---------------- Flash attention (causal), per (q-tile 128, bh) block ----------------
// grid (16 qt, 32 bh), block 256 = 4 waves; wave owns 32 q rows
__global__ __launch_bounds__(256, 2)
void k_attn(const unsigned short* __restrict__ q,     // [4096,3072] roped
            const unsigned short* __restrict__ kv,    // [4096,4096]
            const unsigned short* __restrict__ ckv,   // [4096,576] cols 512.. = roped k_pe
            const unsigned short* __restrict__ vt,    // [32][128][2048]
            unsigned short* __restrict__ ao)          // [4096,2048]
{
    const int qt = blockIdx.x, bh = blockIdx.y;
    const int b = bh >> 4, h = bh & 15;
    const int tid = threadIdx.x, wave = tid >> 6, lane = tid & 63;
    const int lrow = lane & 15, quad = lane >> 4, lko = quad * 8;
    __shared__ __align__(16) unsigned short Pl[4][32][136];

    // Q fragments in registers (rows wave*32 + mi*16 + lrow)
    short8 qf[2][6];
#pragma unroll
    for (int mi = 0; mi < 2; mi++) {
        int tok = b * 2048 + qt * 128 + wave * 32 + mi * 16 + lrow;
        const unsigned short* qp = q + (size_t)tok * 3072 + h * 192;
#pragma unroll
        for (int ks = 0; ks < 6; ks++) qf[mi][ks] = *(const short8*)(qp + ks * 32 + lko);
    }

    float m_st[8], l_st[8];
#pragma unroll
    for (int i = 0; i < 8; i++) {
        m_st[i] = -__builtin_inff();
        l_st[i] = 0.f;
    }
    float4v zero4 = {0.f, 0.f, 0.f, 0.f};
    float4v o[2][8];
#pragma unroll
    for (int mi = 0; mi < 2; mi++)
#pragma unroll
        for (int dt = 0; dt < 8; dt++) o[mi][dt] = zero4;

    const float scale = 0.07216878364870323f;  // 192^-0.5

    for (int kt = 0; kt <= qt; ++kt) {
        float4v sc[2][8];
#pragma unroll
        for (int mi = 0; mi < 2; mi++)
#pragma unroll
            for (int nt = 0; nt < 8; nt++) sc[mi][nt] = zero4;

#pragma unroll
        for (int ks = 0; ks < 6; ks++) {
#pragma unroll
            for (int nt = 0; nt < 8; nt++) {
                int key = b * 2048 + kt * 128 + nt * 16 + lrow;
                short8 kf;
                if (ks < 4)
                    kf = *(const short8*)(kv + (size_t)key * 4096 + h * 256 + ks * 32 + lko);
                else
                    kf = *(const short8*)(ckv + (size_t)key * 576 + 512 + (ks - 4) * 32 + lko);
                sc[0][nt] = __builtin_amdgcn_mfma_f32_16x16x32_bf16(qf[0][ks], kf, sc[0][nt], 0, 0, 0);
                sc[1][nt] = __builtin_amdgcn_mfma_f32_16x16x32_bf16(qf[1][ks], kf, sc[1][nt], 0, 0, 0);
            }
        }

        // scale + causal mask (diagonal tile only)
        const bool diag = (kt == qt);
#pragma unroll
        for (int mi = 0; mi < 2; mi++)
#pragma unroll
            for (int nt = 0; nt < 8; nt++)
#pragma unroll
                for (int r = 0; r < 4; r++) {
                    float v = sc[mi][nt][r] * scale;
                    if (diag) {
                        int ct = nt * 16 + lrow;
                        int rt = wave * 32 + mi * 16 + quad * 4 + r;
                        if (ct > rt) v = -__builtin_inff();
                    }
                    sc[mi][nt][r] = v;
                }

        // online softmax per row (mi, r); cols of a row live on the 16 lanes of this quad
        float alpha[8];
#pragma unroll
        for (int mi = 0; mi < 2; mi++)
#pragma unroll
            for (int r = 0; r < 4; r++) {
                int si = mi * 4 + r;
                float mx = sc[mi][0][r];
#pragma unroll
                for (int nt = 1; nt < 8; nt++) mx = fmaxf(mx, sc[mi][nt][r]);
                mx = fmaxf(mx, __shfl_xor(mx, 1));
                mx = fmaxf(mx, __shfl_xor(mx, 2));
                mx = fmaxf(mx, __shfl_xor(mx, 4));
                mx = fmaxf(mx, __shfl_xor(mx, 8));
                float mnew = fmaxf(m_st[si], mx);
                float a = __expf(m_st[si] - mnew);
                m_st[si] = mnew;
                float rs = 0.f;
#pragma unroll
                for (int nt = 0; nt < 8; nt++) {
                    float p = __expf(sc[mi][nt][r] - mnew);
                    rs += p;
                    Pl[wave][mi * 16 + quad * 4 + r][nt * 16 + lrow] = f2b(p);
                }
                rs += __shfl_xor(rs, 1);
                rs += __shfl_xor(rs, 2);
                rs += __shfl_xor(rs, 4);
                rs += __shfl_xor(rs, 8);
                l_st[si] = l_st[si] * a + rs;
                alpha[si] = a;
            }

        // rescale O
#pragma unroll
        for (int mi = 0; mi < 2; mi++)
#pragma unroll
            for (int dt = 0; dt < 8; dt++)
#pragma unroll
                for (int r = 0; r < 4; r++) o[mi][dt][r] *= alpha[mi * 4 + r];

        // O += P @ V   (P from per-wave LDS, V^T fragments from global)
#pragma unroll
        for (int ks2 = 0; ks2 < 4; ks2++) {
            short8 pa0 = *(const short8*)&Pl[wave][lrow][ks2 * 32 + lko];
            short8 pa1 = *(const short8*)&Pl[wave][16 + lrow][ks2 * 32 + lko];
#pragma unroll
            for (int dt = 0; dt < 8; dt++) {
                short8 vf = *(const short8*)(vt + ((size_t)bh * 128 + dt * 16 + lrow) * 2048 +
                                             kt * 128 + ks2 * 32 + lko);
                o[0][dt] = __builtin_amdgcn_mfma_f32_16x16x32_bf16(pa0, vf, o[0][dt], 0, 0, 0);
                o[1][dt] = __builtin_amdgcn_mfma_f32_16x16x32_bf16(pa1, vf, o[1][dt], 0, 0, 0);
            }
        }
    }

    // finalize: O /= l, write ao[token, h*128 + d]
#pragma unroll
    for (int mi = 0; mi < 2; mi++) {
        int tokbase = b * 2048 + qt * 128 + wave * 32 + mi * 16 + quad * 4;
#pragma unroll
        for (int r = 0; r < 4; r++) {
            float inv = 1.f / l_st[mi * 4 + r];
            unsigned short* dst = ao + (size_t)(tokbase + r) * 2048 + h * 128;
#pragma unroll
            for (int dt = 0; dt < 8; dt++) dst[dt * 16 + lrow] = f2b(o[mi][dt][r] * inv);
        }
    }
}

extern "C" void kernel_launch(void* const* d_in, const int* in_sizes, int n_in,
                              void* d_out, int out_size, void* d_ws, size_t ws_size,
                              hipStream_t stream) {
    (void)in_sizes; (void)n_in; (void)out_size; (void)ws_size;
    const float* hs    = (const float*)d_in[0];
    const float* w_qa  = (const float*)d_in[1];
    const float* g_qa  = (const float*)d_in[2];
    const float* w_qb  = (const float*)d_in[3];
    const float* w_kva = (const float*)d_in[4];
    const float* g_kva = (const float*)d_in[5];
    const float* w_kvb = (const float*)d_in[6];
    const float* w_o   = (const float*)d_in[7];

    char* ws = (char*)d_ws;
    size_t off = 0;
    auto alloc = [&](size_t bytes) -> unsigned short* {
        unsigned short* p = (unsigned short*)(ws + off);
        off += (bytes + 255) & ~(size_t)255;
        return p;
    };
    unsigned short* hb    = alloc(4096ull * 2048 * 2);  // hidden bf16
    unsigned short* wqa   = alloc(1536ull * 2048 * 2);
    unsigned short* wqb   = alloc(3072ull * 1536 * 2);
    unsigned short* wkva  = alloc(576ull * 2048 * 2);
    unsigned short* wkvb  = alloc(4096ull * 512 * 2);
    unsigned short* wo    = alloc(2048ull * 2048 * 2);
    unsigned short* qa    = alloc(4096ull * 1536 * 2);  // q_a, then rmsnormed in place
    unsigned short* ckv   = alloc(4096ull * 576 * 2);   // ckv; cols<512 normed, >=512 roped
    unsigned short* qbuf  = alloc(4096ull * 3072 * 2);  // q, roped in place
    unsigned short* kvbuf = alloc(4096ull * 4096 * 2);  // k_nope | v
    unsigned short* vtb   = alloc(32ull * 128 * 2048 * 2);
    unsigned short* ao    = alloc(4096ull * 2048 * 2);

    auto cvt = [&](const float* src, unsigned short* dst, int n) {
        k_f2b<<<dim3((n / 4 + 255) / 256), dim3(256), 0, stream>>>(src, dst, n);
    };
    cvt(hs, hb, 4096 * 2048);
    cvt(w_qa, wqa, 1536 * 2048);
    cvt(w_qb, wqb, 3072 * 1536);
    cvt(w_kva, wkva, 576 * 2048);
    cvt(w_kvb, wkvb, 4096 * 512);
    cvt(w_o, wo, 2048 * 2048);

    // q_a = hidden @ w_qa^T ; ckv = hidden @ w_kva^T
    k_gemm_bt<<<dim3(12, 32), 256, 0, stream>>>(hb, 2048, wqa, qa, 1536, 1536, 2048, 0);
    k_gemm_bt<<<dim3(5, 32), 256, 0, stream>>>(hb, 2048, wkva, ckv, 576, 576, 2048, 0);
    // rmsnorms (in place) + k_pe rope (in place, disjoint cols)
    k_rmsnorm<<<dim3(4096), 256, 0, stream>>>(qa, g_qa, 1536, 1536);
    k_rmsnorm<<<dim3(4096), 256, 0, stream>>>(ckv, g_kva, 576, 512);
    k_rope_k<<<dim3(512), 256, 0, stream>>>(ckv);
    // q = qa_n @ w_qb^T ; rope q_pe in place
    k_gemm_bt<<<dim3(24, 32), 256, 0, stream>>>(qa, 1536, wqb, qbuf, 3072, 3072, 1536, 0);
    k_rope_q<<<dim3(8192), 256, 0, stream>>>(qbuf);
    // kv = ckv_n @ w_kvb^T
    k_gemm_bt<<<dim3(32, 32), 256, 0, stream>>>(ckv, 576, wkvb, kvbuf, 4096, 4096, 512, 0);
    // v^T
    k_transpose_v<<<dim3(64, 4, 32), 256, 0, stream>>>(kvbuf, vtb);
    // attention
    k_attn<<<dim3(16, 32), 256, 0, stream>>>(qbuf, kvbuf, ckv, vtb, ao);
    // final = ao @ w_o^T -> fp32 d_out
    k_gemm_bt<<<dim3(16, 32), 256, 0, stream>>>(ao, 2048, wo, d_out, 2048, 2048, 2048, 1);
}

// Round 2
// 569.504 us; speedup vs baseline: 1.4483x; 1.4483x over previous
//
#include <hip/hip_runtime.h>
#include <cstdint>
#include <cstring>

typedef short short8 __attribute__((ext_vector_type(8)));
typedef float float4v __attribute__((ext_vector_type(4)));
typedef float float4g __attribute__((ext_vector_type(4)));
typedef unsigned short ushort4v __attribute__((ext_vector_type(4)));

typedef __attribute__((address_space(3))) unsigned int lds_uint;
typedef __attribute__((address_space(1))) const unsigned int glob_uint;

static __device__ __forceinline__ void async16(void* lds, const void* g) {
    // one global_load_lds_dwordx4: 64 lanes x 16B -> LDS at (uniform base + lane*16)
    __builtin_amdgcn_global_load_lds((glob_uint*)g, (lds_uint*)lds, 16, 0, 0);
}

static __device__ __forceinline__ float b2f(unsigned short u) {
    unsigned int x = ((unsigned int)u) << 16;
    float f;
    __builtin_memcpy(&f, &x, 4);
    return f;
}
static __device__ __forceinline__ unsigned short f2b(float f) {
    unsigned int x;
    __builtin_memcpy(&x, &f, 4);
    unsigned int r = (x + 0x7fffu + ((x >> 16) & 1u)) >> 16;
    return (unsigned short)r;
}

// ---------------- fp32 -> bf16 convert ----------------
__global__ __launch_bounds__(256) void k_f2b(const float* __restrict__ in,
                                             unsigned short* __restrict__ out, int n) {
    int i = (blockIdx.x * 256 + threadIdx.x) * 4;
    if (i >= n) return;
    float4g v = *(const float4g*)(in + i);
    ushort4v r;
    r.x = f2b(v.x); r.y = f2b(v.y); r.z = f2b(v.z); r.w = f2b(v.w);
    *(ushort4v*)(out + i) = r;
}

// ---------------- bf16 GEMM (m97 recipe): C[M,N] = A[M,K] @ W[N,K]^T ----------------
// grid: (ceil(N/128), M/128), block 256 (4 waves, each 64x64)
// LDS tiles chunked [row][32] (64B rows) so global_load_lds width=16 lands contiguously
__global__ __launch_bounds__(256, 3)
void k_gemm_bt(const unsigned short* __restrict__ A, int lda,
               const unsigned short* __restrict__ W,
               void* __restrict__ C, int ldc,
               int N, int K, int c_fp32) {
    __shared__ __align__(16) unsigned short As[128 * 32];
    __shared__ __align__(16) unsigned short Ws[128 * 32];
    const int tid = threadIdx.x;
    const int m0 = blockIdx.y * 128, n0 = blockIdx.x * 128;
    const int wave = tid >> 6, lane = tid & 63;
    const int wm = (wave >> 1) * 64, wn = (wave & 1) * 64;
    const int lrow = lane & 15, quad = lane >> 4;
    const int srow = lane >> 2, spiece = lane & 3;

    float4v acc[4][4];
    float4v z = {0.f, 0.f, 0.f, 0.f};
#pragma unroll
    for (int i = 0; i < 4; i++)
#pragma unroll
        for (int j = 0; j < 4; j++) acc[i][j] = z;

    for (int k0 = 0; k0 < K; k0 += 32) {
#pragma unroll
        for (int ii = 0; ii < 2; ++ii) {
            int i = wave + ii * 4;              // 8 instrs cover 128 rows (16 rows each)
            int row = i * 16 + srow;
            async16(&As[i * 512], &A[(size_t)(m0 + row) * lda + k0 + spiece * 8]);
            int wr = n0 + row;
            if (wr > N - 1) wr = N - 1;
            async16(&Ws[i * 512], &W[(size_t)wr * K + k0 + spiece * 8]);
        }
        __syncthreads();
        short8 af[4], bfr[4];
#pragma unroll
        for (int i = 0; i < 4; i++)
            af[i] = *(const short8*)&As[(wm + i * 16 + lrow) * 32 + quad * 8];
#pragma unroll
        for (int i = 0; i < 4; i++)
            bfr[i] = *(const short8*)&Ws[(wn + i * 16 + lrow) * 32 + quad * 8];
#pragma unroll
        for (int i = 0; i < 4; i++)
#pragma unroll
            for (int j = 0; j < 4; j++)
                acc[i][j] = __builtin_amdgcn_mfma_f32_16x16x32_bf16(af[i], bfr[j], acc[i][j], 0, 0, 0);
        __syncthreads();
    }

    const int rbase = quad * 4;
#pragma unroll
    for (int i = 0; i < 4; i++) {
#pragma unroll
        for (int j = 0; j < 4; j++) {
            int col = n0 + wn + j * 16 + lrow;
            if (col >= N) continue;
#pragma unroll
            for (int r = 0; r < 4; r++) {
                int row = m0 + wm + i * 16 + rbase + r;
                float v = acc[i][j][r];
                if (c_fp32)
                    ((float*)C)[(size_t)row * ldc + col] = v;
                else
                    ((unsigned short*)C)[(size_t)row * ldc + col] = f2b(v);
            }
        }
    }
}

// ---------------- RMSNorm in-place over first n cols of a row (stride ld) ----------------
__global__ __launch_bounds__(256) void k_rmsnorm(unsigned short* __restrict__ x,
                                                 const float* __restrict__ g, int ld, int n) {
    int row = blockIdx.x;
    int tid = threadIdx.x;
    size_t base = (size_t)row * ld;
    float ss = 0.f;
    for (int c = tid; c < n; c += 256) {
        float v = b2f(x[base + c]);
        ss += v * v;
    }
    for (int off = 32; off > 0; off >>= 1) ss += __shfl_xor(ss, off);
    __shared__ float wsum[4];
    int wave = tid >> 6, lane = tid & 63;
    if (lane == 0) wsum[wave] = ss;
    __syncthreads();
    ss = wsum[0] + wsum[1] + wsum[2] + wsum[3];
    float scale = rsqrtf(ss / (float)n + 1e-6f);
    for (int c = tid; c < n; c += 256) {
        float v = b2f(x[base + c]);
        x[base + c] = f2b(v * scale * g[c]);
    }
}

// ---------------- RoPE on q_pe ----------------
__global__ __launch_bounds__(256) void k_rope_q(unsigned short* __restrict__ q) {
    int idx = blockIdx.x * 256 + threadIdx.x;  // 4096*16*32
    int d = idx & 31;
    int h = (idx >> 5) & 15;
    int t = idx >> 9;
    int s = t & 2047;
    size_t base = (size_t)t * 3072 + h * 192 + 128;
    float inv = powf(10000.0f, -(float)(2 * d) * (1.0f / 64.0f));
    float f = (float)s * inv;
    float c = cosf(f), sn = sinf(f);
    float x1 = b2f(q[base + d]), x2 = b2f(q[base + d + 32]);
    q[base + d] = f2b(x1 * c - x2 * sn);
    q[base + d + 32] = f2b(x2 * c + x1 * sn);
}

// ---------------- RoPE on k_pe ----------------
__global__ __launch_bounds__(256) void k_rope_k(unsigned short* __restrict__ ckv) {
    int idx = blockIdx.x * 256 + threadIdx.x;  // 4096*32
    int d = idx & 31;
    int t = idx >> 5;
    int s = t & 2047;
    size_t base = (size_t)t * 576 + 512;
    float inv = powf(10000.0f, -(float)(2 * d) * (1.0f / 64.0f));
    float f = (float)s * inv;
    float c = cosf(f), sn = sinf(f);
    float x1 = b2f(ckv[base + d]), x2 = b2f(ckv[base + d + 32]);
    ckv[base + d] = f2b(x1 * c - x2 * sn);
    ckv[base + d + 32] = f2b(x2 * c + x1 * sn);
}

// ---------------- V transpose: vt[bh][d][s] ----------------
__global__ __launch_bounds__(256) void k_transpose_v(const unsigned short* __restrict__ kv,
                                                     unsigned short* __restrict__ vt) {
    int bh = blockIdx.z;
    int b = bh >> 4, h = bh & 15;
    int s0 = blockIdx.x * 32, d0 = blockIdx.y * 32;
    __shared__ unsigned short t[32][33];
    int tx = threadIdx.x & 31, ty = threadIdx.x >> 5;
#pragma unroll
    for (int i = 0; i < 4; i++) {
        int s = s0 + ty + i * 8;
        t[ty + i * 8][tx] = kv[(size_t)(b * 2048 + s) * 4096 + h * 256 + 128 + d0 + tx];
    }
    __syncthreads();
#pragma unroll
    for (int i = 0; i < 4; i++) {
        int d = d0 + ty + i * 8;
        vt[((size_t)bh * 128 + d) * 2048 + s0 + tx] = t[tx][ty + i * 8];
    }
}

// ---------------- Flash attention v2 ----------------
// 512 blocks (1D). Block -> (qt, bh) with pairing so co-resident blocks l and l+256
// have qt and 15-qt (uniform per-CU work). Block = 4 waves, wave owns 32 q rows (mi=2).
// Per kt-step (64 keys): stage K(64x192) + V^T(128x64) in LDS via global_load_lds,
// QK from LDS (2x reuse), online softmax, P -> per-wave swizzled LDS, PV from LDS.
__global__ __launch_bounds__(256, 2)
void k_attn2(const unsigned short* __restrict__ q,     // [4096,3072] roped
             const unsigned short* __restrict__ kv,    // [4096,4096] k_nope|v
             const unsigned short* __restrict__ ckv,   // [4096,576] cols 512.. roped k_pe
             const unsigned short* __restrict__ vt,    // [32][128][2048]
             unsigned short* __restrict__ ao)          // [4096,2048]
{
    __shared__ __align__(16) unsigned short Ks[6 * 64 * 32];    // 24KB [ks][key64][32]
    __shared__ __align__(16) unsigned short Vs[2 * 128 * 32];   // 16KB [ks2][d128][32]
    __shared__ __align__(16) unsigned short Pl[4][2 * 32 * 32]; // 16KB per-wave P

    const int lb = blockIdx.x;
    const int hi = lb >> 8;
    const int qt = hi ? (15 - (lb & 15)) : (lb & 15);
    const int bh = ((lb & 255) >> 4) + (hi << 4);
    const int b = bh >> 4, h = bh & 15;
    const int tid = threadIdx.x, wave = tid >> 6, lane = tid & 63;
    const int lrow = lane & 15, quad = lane >> 4;
    const int srow = lane >> 2, spiece = lane & 3;
    const int tok0 = b * 2048 + qt * 128;

    // Q fragments in registers
    short8 qf[2][6];
#pragma unroll
    for (int mi = 0; mi < 2; mi++) {
        const unsigned short* qp =
            q + (size_t)(tok0 + wave * 32 + mi * 16 + lrow) * 3072 + h * 192;
#pragma unroll
        for (int ks = 0; ks < 6; ks++) qf[mi][ks] = *(const short8*)(qp + ks * 32 + quad * 8);
    }

    float m_st[8], l_st[8], alpha[8];
#pragma unroll
    for (int i = 0; i < 8; i++) {
        m_st[i] = -__builtin_inff();
        l_st[i] = 0.f;
    }
    float4v z4 = {0.f, 0.f, 0.f, 0.f};
    float4v o[2][8];
#pragma unroll
    for (int mi = 0; mi < 2; mi++)
#pragma unroll
        for (int dt = 0; dt < 8; dt++) o[mi][dt] = z4;

    const float scale = 0.07216878364870323f;  // 192^-0.5
    const int nk = 2 * qt + 2;                 // 64-key steps

    for (int kt = 0; kt < nk; ++kt) {
        const int kb = kt * 64;
        // ---- stage K: 24 instrs, 6/wave ----
#pragma unroll
        for (int ii = 0; ii < 6; ++ii) {
            int id = wave * 6 + ii;
            int ks = id >> 2;
            int row = (id & 3) * 16 + srow;
            int key = b * 2048 + kb + row;
            const unsigned short* g =
                (ks < 4) ? kv + (size_t)key * 4096 + h * 256 + ks * 32 + spiece * 8
                         : ckv + (size_t)key * 576 + 512 + (ks - 4) * 32 + spiece * 8;
            async16(&Ks[id * 512], g);
        }
        // ---- stage V^T: 16 instrs, 4/wave ----
#pragma unroll
        for (int ii = 0; ii < 4; ++ii) {
            int id = wave * 4 + ii;
            int d = (id & 7) * 16 + srow;
            const unsigned short* g =
                vt + ((size_t)bh * 128 + d) * 2048 + kb + (id >> 3) * 32 + spiece * 8;
            async16(&Vs[id * 512], g);
        }
        __syncthreads();

        // ---- QK^T ----
        float4v sc[2][4];
#pragma unroll
        for (int mi = 0; mi < 2; mi++)
#pragma unroll
            for (int nt = 0; nt < 4; nt++) sc[mi][nt] = z4;
#pragma unroll
        for (int ks = 0; ks < 6; ks++) {
#pragma unroll
            for (int nt = 0; nt < 4; nt++) {
                short8 kf = *(const short8*)&Ks[ks * 2048 + (nt * 16 + lrow) * 32 + quad * 8];
                sc[0][nt] = __builtin_amdgcn_mfma_f32_16x16x32_bf16(qf[0][ks], kf, sc[0][nt], 0, 0, 0);
                sc[1][nt] = __builtin_amdgcn_mfma_f32_16x16x32_bf16(qf[1][ks], kf, sc[1][nt], 0, 0, 0);
            }
        }

        // ---- scale + causal mask (only near the diagonal) ----
        const bool edge = (kt >= nk - 2);
#pragma unroll
        for (int mi = 0; mi < 2; mi++)
#pragma unroll
            for (int nt = 0; nt < 4; nt++)
#pragma unroll
                for (int r = 0; r < 4; r++) {
                    float v = sc[mi][nt][r] * scale;
                    if (edge) {
                        int keyc = kb + nt * 16 + lrow;
                        int rowc = qt * 128 + wave * 32 + mi * 16 + quad * 4 + r;
                        if (keyc > rowc) v = -__builtin_inff();
                    }
                    sc[mi][nt][r] = v;
                }

        // ---- online softmax; P into per-wave swizzled LDS ----
#pragma unroll
        for (int mi = 0; mi < 2; mi++)
#pragma unroll
            for (int r = 0; r < 4; r++) {
                int si = mi * 4 + r;
                float mx = sc[mi][0][r];
#pragma unroll
                for (int nt = 1; nt < 4; nt++) mx = fmaxf(mx, sc[mi][nt][r]);
                mx = fmaxf(mx, __shfl_xor(mx, 1));
                mx = fmaxf(mx, __shfl_xor(mx, 2));
                mx = fmaxf(mx, __shfl_xor(mx, 4));
                mx = fmaxf(mx, __shfl_xor(mx, 8));
                float mnew = fmaxf(m_st[si], mx);
                float a = __expf(m_st[si] - mnew);
                m_st[si] = mnew;
                int prow = mi * 16 + quad * 4 + r;
                float rs = 0.f;
#pragma unroll
                for (int nt = 0; nt < 4; nt++) {
                    float p = __expf(sc[mi][nt][r] - mnew);
                    rs += p;
                    int piece = (nt & 1) * 2 + (lrow >> 3);
                    Pl[wave][(nt >> 1) * 1024 + prow * 32 + ((piece ^ quad) * 8) + (lrow & 7)] =
                        f2b(p);
                }
                rs += __shfl_xor(rs, 1);
                rs += __shfl_xor(rs, 2);
                rs += __shfl_xor(rs, 4);
                rs += __shfl_xor(rs, 8);
                l_st[si] = l_st[si] * a + rs;
                alpha[si] = a;
            }

        // ---- rescale O ----
#pragma unroll
        for (int mi = 0; mi < 2; mi++)
#pragma unroll
            for (int dt = 0; dt < 8; dt++)
#pragma unroll
                for (int r = 0; r < 4; r++) o[mi][dt][r] *= alpha[mi * 4 + r];

        // ---- O += P @ V ----
#pragma unroll
        for (int ks2 = 0; ks2 < 2; ks2++) {
            short8 pa[2];
#pragma unroll
            for (int mi = 0; mi < 2; mi++) {
                int pc = quad ^ ((lrow >> 2) & 3);
                pa[mi] = *(const short8*)&Pl[wave][ks2 * 1024 + (mi * 16 + lrow) * 32 + pc * 8];
            }
#pragma unroll
            for (int dt = 0; dt < 8; dt++) {
                short8 vf = *(const short8*)&Vs[ks2 * 4096 + (dt * 16 + lrow) * 32 + quad * 8];
                o[0][dt] = __builtin_amdgcn_mfma_f32_16x16x32_bf16(pa[0], vf, o[0][dt], 0, 0, 0);
                o[1][dt] = __builtin_amdgcn_mfma_f32_16x16x32_bf16(pa[1], vf, o[1][dt], 0, 0, 0);
            }
        }
        __syncthreads();
    }

    // ---- finalize ----
#pragma unroll
    for (int mi = 0; mi < 2; mi++) {
#pragma unroll
        for (int r = 0; r < 4; r++) {
            float inv = 1.f / l_st[mi * 4 + r];
            unsigned short* dst =
                ao + (size_t)(tok0 + wave * 32 + mi * 16 + quad * 4 + r) * 2048 + h * 128;
#pragma unroll
            for (int dt = 0; dt < 8; dt++) dst[dt * 16 + lrow] = f2b(o[mi][dt][r] * inv);
        }
    }
}

extern "C" void kernel_launch(void* const* d_in, const int* in_sizes, int n_in,
                              void* d_out, int out_size, void* d_ws, size_t ws_size,
                              hipStream_t stream) {
    (void)in_sizes; (void)n_in; (void)out_size; (void)ws_size;
    const float* hs    = (const float*)d_in[0];
    const float* w_qa  = (const float*)d_in[1];
    const float* g_qa  = (const float*)d_in[2];
    const float* w_qb  = (const float*)d_in[3];
    const float* w_kva = (const float*)d_in[4];
    const float* g_kva = (const float*)d_in[5];
    const float* w_kvb = (const float*)d_in[6];
    const float* w_o   = (const float*)d_in[7];

    char* ws = (char*)d_ws;
    size_t off = 0;
    auto alloc = [&](size_t bytes) -> unsigned short* {
        unsigned short* p = (unsigned short*)(ws + off);
        off += (bytes + 255) & ~(size_t)255;
        return p;
    };
    unsigned short* hb    = alloc(4096ull * 2048 * 2);
    unsigned short* wqa   = alloc(1536ull * 2048 * 2);
    unsigned short* wqb   = alloc(3072ull * 1536 * 2);
    unsigned short* wkva  = alloc(576ull * 2048 * 2);
    unsigned short* wkvb  = alloc(4096ull * 512 * 2);
    unsigned short* wo    = alloc(2048ull * 2048 * 2);
    unsigned short* qa    = alloc(4096ull * 1536 * 2);
    unsigned short* ckv   = alloc(4096ull * 576 * 2);
    unsigned short* qbuf  = alloc(4096ull * 3072 * 2);
    unsigned short* kvbuf = alloc(4096ull * 4096 * 2);
    unsigned short* vtb   = alloc(32ull * 128 * 2048 * 2);
    unsigned short* ao    = alloc(4096ull * 2048 * 2);

    auto cvt = [&](const float* src, unsigned short* dst, int n) {
        k_f2b<<<dim3((n / 4 + 255) / 256), dim3(256), 0, stream>>>(src, dst, n);
    };
    cvt(hs, hb, 4096 * 2048);
    cvt(w_qa, wqa, 1536 * 2048);
    cvt(w_qb, wqb, 3072 * 1536);
    cvt(w_kva, wkva, 576 * 2048);
    cvt(w_kvb, wkvb, 4096 * 512);
    cvt(w_o, wo, 2048 * 2048);

    k_gemm_bt<<<dim3(12, 32), 256, 0, stream>>>(hb, 2048, wqa, qa, 1536, 1536, 2048, 0);
    k_gemm_bt<<<dim3(5, 32), 256, 0, stream>>>(hb, 2048, wkva, ckv, 576, 576, 2048, 0);
    k_rmsnorm<<<dim3(4096), 256, 0, stream>>>(qa, g_qa, 1536, 1536);
    k_rmsnorm<<<dim3(4096), 256, 0, stream>>>(ckv, g_kva, 576, 512);
    k_rope_k<<<dim3(512), 256, 0, stream>>>(ckv);
    k_gemm_bt<<<dim3(24, 32), 256, 0, stream>>>(qa, 1536, wqb, qbuf, 3072, 3072, 1536, 0);
    k_rope_q<<<dim3(8192), 256, 0, stream>>>(qbuf);
    k_gemm_bt<<<dim3(32, 32), 256, 0, stream>>>(ckv, 576, wkvb, kvbuf, 4096, 4096, 512, 0);
    k_transpose_v<<<dim3(64, 4, 32), 256, 0, stream>>>(kvbuf, vtb);
    k_attn2<<<dim3(512), 256, 0, stream>>>(qbuf, kvbuf, ckv, vtb, ao);
    k_gemm_bt<<<dim3(16, 32), 256, 0, stream>>>(ao, 2048, wo, d_out, 2048, 2048, 2048, 1);
}